// Round 6
// baseline (2287.748 us; speedup 1.0000x reference)
//
#include <hip/hip_runtime.h>

typedef unsigned short u16;
typedef unsigned int   u32;
typedef short s16x8 __attribute__((ext_vector_type(8)));
typedef float f32x4 __attribute__((ext_vector_type(4)));

#define DI __device__ __forceinline__

DI float b2f(u16 u){ union{u32 i; float f;} x; x.i = ((u32)u)<<16; return x.f; }
DI u16 f2bf(float f){ union{float f; u32 i;} x; x.f=f; u32 r = x.i + 0x7FFFu + ((x.i>>16)&1u); return (u16)(r>>16); }
DI float sigf(float x){ return 1.0f/(1.0f + __expf(-x)); }
DI float tanh_(float x){ return 1.0f - 2.0f/(__expf(2.0f*x)+1.0f); }
DI float dot4(float4 a, float4 b){ return a.x*b.x + a.y*b.y + a.z*b.z + a.w*b.w; }

// ---------------- conv1 (k=7,pad3) + BN1 + ReLU + maxpool2 ----------------
// x: [128][2048][8] f32  -> out: [128][128][1024] f32  (layout [b][co][t'])
__global__ __launch_bounds__(256) void k_conv1(
    const float* __restrict__ x, const float* __restrict__ w,
    const float* __restrict__ cb, const float* __restrict__ bg, const float* __restrict__ bb,
    const float* __restrict__ bm, const float* __restrict__ bv, float* __restrict__ out)
{
  __shared__ __align__(16) float xs[262*8];
  __shared__ __align__(16) float wl[128*7*8];   // [co][k][ci]
  __shared__ float As[128], Ss[128];
  const int tid = threadIdx.x;
  const int tc  = blockIdx.x;
  const int b   = blockIdx.y;
  const int tau0 = tc*256;
  for(int f = tid; f < 262*8; f += 256){
    int tt = f >> 3;
    int ci = f & 7;
    int xg = tau0 - 3 + tt;
    float val = 0.f;
    if(xg >= 0 && xg < 2048) val = x[(b*2048 + xg)*8 + ci];
    xs[f] = val;
  }
  for(int d = tid; d < 128*7*8; d += 256){
    int co = d / 56; int r = d - co*56; int k = r >> 3; int ci = r & 7;
    wl[d] = w[(co*8 + ci)*7 + k];
  }
  if(tid < 128){
    float a = bg[tid] * rsqrtf(bv[tid] + 1e-5f);
    As[tid] = a;
    Ss[tid] = (cb[tid] - bm[tid])*a + bb[tid];
  }
  __syncthreads();
  const float4* xs4 = (const float4*)xs;
  const float4* wl4 = (const float4*)wl;
  for(int i = 0; i < 64; i++){
    int idx = i*256 + tid;
    int co = idx >> 7, p = idx & 127;
    float4 xa[8], xb[8];
    #pragma unroll
    for(int d=0; d<8; d++){ xa[d] = xs4[(2*p + d)*2]; xb[d] = xs4[(2*p + d)*2 + 1]; }
    float a0 = 0.f, a1 = 0.f;
    #pragma unroll
    for(int k=0;k<7;k++){
      float4 wa = wl4[(co*7+k)*2], wb = wl4[(co*7+k)*2+1];
      a0 += dot4(xa[k],   wa) + dot4(xb[k],   wb);
      a1 += dot4(xa[k+1], wa) + dot4(xb[k+1], wb);
    }
    float Ac = As[co], Sc = Ss[co];
    float y = fmaxf(fmaxf(a0*Ac+Sc, a1*Ac+Sc), 0.f);
    out[((b*128 + co)<<10) + tc*128 + p] = y;
  }
}

// ---------------- conv2 + BN2 + ReLU + maxpool2 — MFMA, split A & W ----------------
// in: [128][128][1024] f32, w: [256][128][5] f32 -> seq: [512][128][256] f32
__global__ __launch_bounds__(256) void k_conv2(
    const float* __restrict__ cin, const float* __restrict__ w,
    const float* __restrict__ cb, const float* __restrict__ bg, const float* __restrict__ bb,
    const float* __restrict__ bm, const float* __restrict__ bv, float* __restrict__ seq)
{
  __shared__ __align__(16) u16 XH[132*136];   // [dt][ci] hi
  __shared__ __align__(16) u16 XL[132*136];   // lo
  __shared__ __align__(16) u16 BH[128*136];   // [co][ci] hi
  __shared__ __align__(16) u16 BL[128*136];   // lo
  const int tid = threadIdx.x;
  const int tc  = blockIdx.x;        // 0..7 (128 pre-pool t each)
  const int co0 = blockIdx.y << 7;   // 0,128
  const int b   = blockIdx.z;
  const int lane = tid & 63, wv = tid >> 6;
  const int m16 = lane & 15, kg = lane >> 4;
  const int woff_m = (wv & 1)*64, woff_n = (wv >> 1)*64;
  float Aj[4], Sj[4];
  #pragma unroll
  for(int j=0;j<4;j++){
    int co = co0 + woff_n + j*16 + m16;
    float a = bg[co]*rsqrtf(bv[co]+1e-5f);
    Aj[j]=a; Sj[j]=(cb[co]-bm[co])*a + bb[co];
  }
  // stage X once (f32 -> hi/lo bf16): rows dt 0..131 <-> input t = tc*128 + dt - 2
  const int tau0 = tc*128;
  for(int f = tid; f < 132*128; f += 256){
    int ci = f / 132, dt = f - ci*132;
    int tg = tau0 + dt - 2;
    float val = 0.f;
    if(tg >= 0 && tg < 1024) val = cin[((b*128+ci)<<10) + tg];
    u16 hi = f2bf(val);
    XH[dt*136 + ci] = hi;
    XL[dt*136 + ci] = f2bf(val - b2f(hi));
  }
  f32x4 acc[4][4];
  #pragma unroll
  for(int i=0;i<4;i++)
    #pragma unroll
    for(int j=0;j<4;j++){ acc[i][j][0]=0.f; acc[i][j][1]=0.f; acc[i][j][2]=0.f; acc[i][j][3]=0.f; }
  for(int k=0;k<5;k++){
    __syncthreads();
    // stage B(k): 128 co x 128 ci from f32 global, split hi/lo
    for(int f = tid; f < 16384; f += 256){
      int co = f >> 7, ci = f & 127;
      float wvv = w[(co0+co)*640 + ci*5 + k];
      u16 hi = f2bf(wvv);
      BH[co*136 + ci] = hi;
      BL[co*136 + ci] = f2bf(wvv - b2f(hi));
    }
    __syncthreads();
    #pragma unroll
    for(int c8=0;c8<4;c8++){
      const int cib = c8*32 + kg*8;
      s16x8 aH[4], aL[4], bH[4], bL[4];
      #pragma unroll
      for(int i=0;i<4;i++){
        int row = (woff_m + i*16 + m16 + k)*136 + cib;
        aH[i] = *(const s16x8*)&XH[row];
        aL[i] = *(const s16x8*)&XL[row];
      }
      #pragma unroll
      for(int j=0;j<4;j++){
        int row = (woff_n + j*16 + m16)*136 + cib;
        bH[j] = *(const s16x8*)&BH[row];
        bL[j] = *(const s16x8*)&BL[row];
      }
      #pragma unroll
      for(int i=0;i<4;i++)
        #pragma unroll
        for(int j=0;j<4;j++){
          acc[i][j] = __builtin_amdgcn_mfma_f32_16x16x32_bf16(aH[i], bH[j], acc[i][j], 0, 0, 0);
          acc[i][j] = __builtin_amdgcn_mfma_f32_16x16x32_bf16(aH[i], bL[j], acc[i][j], 0, 0, 0);
          acc[i][j] = __builtin_amdgcn_mfma_f32_16x16x32_bf16(aL[i], bH[j], acc[i][j], 0, 0, 0);
        }
    }
  }
  // epilogue: BN + ReLU + pool pairs; C/D: col=lane&15 (co), row=(lane>>4)*4+reg (t)
  #pragma unroll
  for(int i=0;i<4;i++){
    int mb = woff_m + i*16 + kg*4;
    int tp = tc*64 + (mb>>1);
    #pragma unroll
    for(int j=0;j<4;j++){
      int co = co0 + woff_n + j*16 + m16;
      float p0 = acc[i][j][0]*Aj[j]+Sj[j], p1 = acc[i][j][1]*Aj[j]+Sj[j];
      float p2 = acc[i][j][2]*Aj[j]+Sj[j], p3 = acc[i][j][3]*Aj[j]+Sj[j];
      seq[(tp*128 + b)*256 + co]     = fmaxf(fmaxf(p0,p1),0.f);
      seq[((tp+1)*128 + b)*256 + co] = fmaxf(fmaxf(p2,p3),0.f);
    }
  }
}

// ---------------- xp chunk = LN(seq @ wih.T + bih), f32 out, 64 steps/chunk ----------------
// dir0 rows: ts=64c+l ; dir1 rows: ts=511-64c-l ; local row = l*128+b
__global__ __launch_bounds__(512) void k_xp(
    const float* __restrict__ seq,
    const float* __restrict__ fw, const float* __restrict__ fbi, const float* __restrict__ fg, const float* __restrict__ fb,
    const float* __restrict__ bw, const float* __restrict__ bbi, const float* __restrict__ bg_, const float* __restrict__ bb_,
    float* __restrict__ xpF, float* __restrict__ xpB, int c)
{
  __shared__ __align__(16) float sT[32*36];     // [k][r] pitch 36
  __shared__ __align__(16) float wT[32*386];    // [k][j] pitch 386
  const float *W, *BI, *LG, *LB; float* out;
  int srow0, drow0;
  const int bx = blockIdx.x;
  if(blockIdx.y == 0){
    W=fw; BI=fbi; LG=fg; LB=fb; out=xpF;
    srow0 = 8192*c + 32*bx; drow0 = 32*bx;
  } else {
    W=bw; BI=bbi; LG=bg_; LB=bb_; out=xpB;
    int l = bx >> 2, b0 = (bx & 3)*32;
    srow0 = (511 - 64*c - l)*128 + b0; drow0 = l*128 + b0;
  }
  const int tid = threadIdx.x;
  const int jg = tid & 63, rg = tid >> 6;
  const int j0 = jg*6;
  float bi6[6], g6[6], b6[6];
  #pragma unroll
  for(int e=0;e<6;e++){ bi6[e]=BI[j0+e]; g6[e]=LG[j0+e]; b6[e]=LB[j0+e]; }
  float acc[4][6];
  #pragma unroll
  for(int r=0;r<4;r++)
    #pragma unroll
    for(int e=0;e<6;e++) acc[r][e]=0.f;
  for(int k0=0;k0<256;k0+=32){
    __syncthreads();
    {
      int r = tid >> 4; int kk = (tid & 15)*2;
      float2 pv = *(const float2*)&seq[(srow0 + r)*256 + k0 + kk];
      sT[kk*36 + r]     = pv.x;
      sT[(kk+1)*36 + r] = pv.y;
    }
    #pragma unroll
    for(int rep=0; rep<24; rep++){
      int flat = rep*512 + tid;
      int j = flat >> 5; int kk = flat & 31;
      wT[kk*386 + j] = W[j*256 + k0 + kk];
    }
    __syncthreads();
    #pragma unroll 8
    for(int kk=0;kk<32;kk++){
      float4 s4 = *(const float4*)&sT[kk*36 + rg*4];
      const float* wp = &wT[kk*386 + j0];
      #pragma unroll
      for(int e=0;e<6;e++){
        float wv = wp[e];
        acc[0][e] += s4.x*wv;
        acc[1][e] += s4.y*wv;
        acc[2][e] += s4.z*wv;
        acc[3][e] += s4.w*wv;
      }
    }
  }
  #pragma unroll
  for(int r=0;r<4;r++){
    float s=0.f, ss=0.f;
    #pragma unroll
    for(int e=0;e<6;e++){
      float u = acc[r][e] + bi6[e];
      acc[r][e] = u;
      s += u; ss += u*u;
    }
    #pragma unroll
    for(int msk=32; msk; msk>>=1){ s += __shfl_xor(s,msk); ss += __shfl_xor(ss,msk); }
    float mean = s * (1.f/384.f);
    float var  = fmaxf(ss * (1.f/384.f) - mean*mean, 0.f);
    float rs = rsqrtf(var + 1e-5f);
    float* op = out + (size_t)(drow0 + rg*4 + r)*384 + j0;
    #pragma unroll
    for(int e=0;e<6;e++) op[e] = (acc[r][e]-mean)*rs*g6[e] + b6[e];
  }
}

// ---------------- LN-LSTM chunk: 64 steps, state carried in global ----------------
__global__ __launch_bounds__(256,1) void k_lstm(
    const float* __restrict__ xpF, const float* __restrict__ xpB,
    const float* __restrict__ fwhh, const float* __restrict__ fbhh, const float* __restrict__ fgh, const float* __restrict__ fbh2,
    const float* __restrict__ fgho, const float* __restrict__ fbho,
    const float* __restrict__ bwhh, const float* __restrict__ bbhh, const float* __restrict__ bgh, const float* __restrict__ bbh2,
    const float* __restrict__ bgho, const float* __restrict__ bbho,
    u16* __restrict__ hcat, float* __restrict__ stateH, float* __restrict__ stateC, int c)
{
  __shared__ __align__(16) float hx[96];
  __shared__ float su[384];
  __shared__ float red2[8];
  const int b   = blockIdx.x;
  const int dir = blockIdx.y;
  const float* xp;
  const float *whh, *bh, *gh, *bh2, *gho, *bho;
  if(dir == 0){ xp=xpF; whh=fwhh; bh=fbhh; gh=fgh; bh2=fbh2; gho=fgho; bho=fbho; }
  else        { xp=xpB; whh=bwhh; bh=bbhh; gh=bgh; bh2=bbh2; gho=bgho; bho=bbho; }
  const int tid  = threadIdx.x;
  const int lane = tid & 63, wv = tid >> 6;
  const int s = lane >> 4, g4 = lane & 15;
  float wr[6][24];
  float bh6[6];
  #pragma unroll
  for(int q=0;q<6;q++){
    int j = wv*16 + g4 + 64*q;
    bh6[q] = bh[j];
    const float4* wp = (const float4*)(whh + j*96 + s*24);
    #pragma unroll
    for(int t4=0;t4<6;t4++){
      float4 v = wp[t4];
      wr[q][4*t4]=v.x; wr[q][4*t4+1]=v.y; wr[q][4*t4+2]=v.z; wr[q][4*t4+3]=v.w;
    }
  }
  const int h1 = lane, h2 = 64 + lane;       // h2 valid iff lane<32
  const int sbase = (dir*128 + b)*96;
  float ghA[4], bhA[4], ghB[4], bhB[4];
  float ghoA=0.f, bhoA=0.f, ghoB=0.f, bhoB=0.f;
  float cxA=0.f, cxB=0.f;
  float xtA[4]={0,0,0,0}, xtB[4]={0,0,0,0};
  if(tid < 96) hx[tid] = (c == 0) ? 0.f : stateH[sbase + tid];
  if(tid < 64){
    #pragma unroll
    for(int p=0;p<4;p++){ ghA[p]=gh[h1+96*p]; bhA[p]=bh2[h1+96*p]; }
    ghoA = gho[h1]; bhoA = bho[h1];
    if(lane < 32){
      #pragma unroll
      for(int p=0;p<4;p++){ ghB[p]=gh[h2+96*p]; bhB[p]=bh2[h2+96*p]; }
      ghoB = gho[h2]; bhoB = bho[h2];
    }
    if(c > 0){
      cxA = stateC[sbase + h1];
      if(lane < 32) cxB = stateC[sbase + h2];
    }
    const float* xr = xp + (size_t)b*384;    // local row l=0
    #pragma unroll
    for(int p=0;p<4;p++) xtA[p] = xr[h1+96*p];
    if(lane < 32){
      #pragma unroll
      for(int p=0;p<4;p++) xtB[p] = xr[h2+96*p];
    }
  }
  __syncthreads();
  for(int l=0; l<64; l++){
    const int ts = dir ? (511 - 64*c - l) : (64*c + l);
    // ---- phase 1: matvec (all 4 waves) ----
    float hv[24];
    {
      const float4* hp = (const float4*)&hx[s*24];
      #pragma unroll
      for(int i=0;i<6;i++){ float4 v = hp[i]; hv[4*i]=v.x; hv[4*i+1]=v.y; hv[4*i+2]=v.z; hv[4*i+3]=v.w; }
    }
    float u[6];
    #pragma unroll
    for(int q=0;q<6;q++){
      float a = 0.f;
      #pragma unroll
      for(int kk=0;kk<24;kk++) a += hv[kk]*wr[q][kk];
      a += __shfl_xor(a,16); a += __shfl_xor(a,32);
      u[q] = a + bh6[q];
    }
    float ps = 0.f, pss = 0.f;
    if(s == 0){
      #pragma unroll
      for(int q=0;q<6;q++){ ps += u[q]; pss += u[q]*u[q]; }
    }
    #pragma unroll
    for(int msk=32; msk; msk>>=1){ ps += __shfl_xor(ps,msk); pss += __shfl_xor(pss,msk); }
    if(lane == 0){ red2[wv*2] = ps; red2[wv*2+1] = pss; }
    if(s == 0){
      #pragma unroll
      for(int q=0;q<6;q++) su[wv*16 + g4 + 64*q] = u[q];
    }
    __syncthreads();
    // ---- phase 2: cell update (wave 0 only) ----
    if(tid < 64){
      const float S  = red2[0]+red2[2]+red2[4]+red2[6];
      const float SS = red2[1]+red2[3]+red2[5]+red2[7];
      const float mean = S*(1.f/384.f);
      const float var  = fmaxf(SS*(1.f/384.f) - mean*mean, 0.f);
      const float rs   = rsqrtf(var + 1e-5f);
      float gi = xtA[0] + (su[h1      ]-mean)*rs*ghA[0] + bhA[0];
      float gf = xtA[1] + (su[h1 +  96]-mean)*rs*ghA[1] + bhA[1];
      float gg = xtA[2] + (su[h1 + 192]-mean)*rs*ghA[2] + bhA[2];
      float go = xtA[3] + (su[h1 + 288]-mean)*rs*ghA[3] + bhA[3];
      float cyA = sigf(gf)*cxA + sigf(gi)*tanh_(gg); cxA = cyA;
      float cyB = 0.f, goB = 0.f;
      if(lane < 32){
        float gi2 = xtB[0] + (su[h2      ]-mean)*rs*ghB[0] + bhB[0];
        float gf2 = xtB[1] + (su[h2 +  96]-mean)*rs*ghB[1] + bhB[1];
        float gg2 = xtB[2] + (su[h2 + 192]-mean)*rs*ghB[2] + bhB[2];
        goB       = xtB[3] + (su[h2 + 288]-mean)*rs*ghB[3] + bhB[3];
        cyB = sigf(gf2)*cxB + sigf(gi2)*tanh_(gg2); cxB = cyB;
      }
      float ps2 = cyA + cyB, pss2 = cyA*cyA + cyB*cyB;
      #pragma unroll
      for(int msk=32; msk; msk>>=1){ ps2 += __shfl_xor(ps2,msk); pss2 += __shfl_xor(pss2,msk); }
      const float m2  = ps2*(1.f/96.f);
      const float v2  = fmaxf(pss2*(1.f/96.f) - m2*m2, 0.f);
      const float rs2 = rsqrtf(v2 + 1e-5f);
      u16* hc = hcat + ((size_t)ts*128 + b)*192 + dir*96;
      float hyA = sigf(go)*tanh_((cyA - m2)*rs2*ghoA + bhoA);
      hx[h1] = hyA; hc[h1] = f2bf(hyA);
      if(lane < 32){
        float hyB = sigf(goB)*tanh_((cyB - m2)*rs2*ghoB + bhoB);
        hx[h2] = hyB; hc[h2] = f2bf(hyB);
      }
      if(l+1 < 64){
        const float* xr = xp + (size_t)((l+1)*128 + b)*384;
        #pragma unroll
        for(int p=0;p<4;p++) xtA[p] = xr[h1+96*p];
        if(lane < 32){
          #pragma unroll
          for(int p=0;p<4;p++) xtB[p] = xr[h2+96*p];
        }
      }
    }
    __syncthreads();
  }
  // save state
  if(tid < 96) stateH[sbase + tid] = hx[tid];
  if(tid < 64){
    stateC[sbase + h1] = cxA;
    if(lane < 32) stateC[sbase + h2] = cxB;
  }
}

// ---------------- attention + fc1/BN3/ReLU + fc2 (one block per batch) ----------------
__global__ __launch_bounds__(256) void k_head(
    const u16* __restrict__ hcat, const float* __restrict__ aw,
    const float* __restrict__ f1w, const float* __restrict__ f1b,
    const float* __restrict__ g3, const float* __restrict__ b3, const float* __restrict__ m3, const float* __restrict__ v3,
    const float* __restrict__ fc2w, const float* __restrict__ fc2bias,
    float* __restrict__ out)
{
  __shared__ float p[512];
  __shared__ float red[8];
  __shared__ __align__(16) float ctx[192];
  __shared__ float h2[256];
  __shared__ float awl[192];
  const int b = blockIdx.x;
  const int tid = threadIdx.x;
  if(tid < 192) awl[tid] = aw[tid];
  __syncthreads();
  float sc0 = 0.f, sc1 = 0.f;
  #pragma unroll
  for(int i=0;i<2;i++){
    int t = i*256 + tid;
    const uint4* hp = (const uint4*)(hcat + ((size_t)t*128 + b)*192);
    float acc = 0.f;
    #pragma unroll 6
    for(int qq=0;qq<24;qq++){
      uint4 pv = hp[qq];
      acc += b2f((u16)(pv.x&0xffffu))*awl[qq*8+0] + b2f((u16)(pv.x>>16))*awl[qq*8+1]
           + b2f((u16)(pv.y&0xffffu))*awl[qq*8+2] + b2f((u16)(pv.y>>16))*awl[qq*8+3]
           + b2f((u16)(pv.z&0xffffu))*awl[qq*8+4] + b2f((u16)(pv.z>>16))*awl[qq*8+5]
           + b2f((u16)(pv.w&0xffffu))*awl[qq*8+6] + b2f((u16)(pv.w>>16))*awl[qq*8+7];
    }
    if(i==0) sc0 = acc; else sc1 = acc;
  }
  float mx = fmaxf(sc0, sc1);
  for(int msk=32; msk; msk>>=1) mx = fmaxf(mx, __shfl_xor(mx,msk));
  if((tid&63)==0) red[tid>>6] = mx;
  __syncthreads();
  mx = fmaxf(fmaxf(red[0],red[1]), fmaxf(red[2],red[3]));
  float e0 = __expf(sc0-mx), e1 = __expf(sc1-mx);
  float sm = e0 + e1;
  for(int msk=32; msk; msk>>=1) sm += __shfl_xor(sm,msk);
  if((tid&63)==0) red[4 + (tid>>6)] = sm;
  __syncthreads();
  const float inv = 1.f/(red[4]+red[5]+red[6]+red[7]);
  p[tid] = e0*inv; p[tid+256] = e1*inv;
  __syncthreads();
  if(tid < 192){
    float acc = 0.f;
    for(int t=0;t<512;t++){
      acc += p[t] * b2f(hcat[((size_t)t*128 + b)*192 + tid]);
    }
    ctx[tid] = acc;
  }
  __syncthreads();
  {
    const float4* cv = (const float4*)ctx;
    const float4* wp = (const float4*)(f1w + tid*192);
    float acc = 0.f;
    #pragma unroll 8
    for(int qq=0;qq<48;qq++){
      acc += dot4(wp[qq], cv[qq]);
    }
    acc += f1b[tid];
    float a = g3[tid] * rsqrtf(v3[tid] + 1e-5f);
    float y = (acc - m3[tid])*a + b3[tid];
    h2[tid] = fmaxf(y, 0.f);
  }
  __syncthreads();
  if(tid < 6){
    float acc = fc2bias[tid];
    for(int k=0;k<256;k++) acc += h2[k]*fc2w[tid*256 + k];
    out[b*6 + tid] = acc;
  }
}

extern "C" void kernel_launch(void* const* d_in, const int* in_sizes, int n_in,
                              void* d_out, int out_size, void* d_ws, size_t ws_size,
                              hipStream_t stream)
{
  (void)in_sizes; (void)n_in; (void)out_size; (void)ws_size;
  const float* X      = (const float*)d_in[0];
  const float* c1w    = (const float*)d_in[1];
  const float* c1b    = (const float*)d_in[2];
  const float* bn1g   = (const float*)d_in[3];
  const float* bn1b   = (const float*)d_in[4];
  const float* bn1m   = (const float*)d_in[5];
  const float* bn1v   = (const float*)d_in[6];
  const float* c2w    = (const float*)d_in[7];
  const float* c2b    = (const float*)d_in[8];
  const float* bn2g   = (const float*)d_in[9];
  const float* bn2b   = (const float*)d_in[10];
  const float* bn2m   = (const float*)d_in[11];
  const float* bn2v   = (const float*)d_in[12];
  const float* fwih   = (const float*)d_in[13];
  const float* fbih   = (const float*)d_in[14];
  const float* fwhh   = (const float*)d_in[15];
  const float* fbhh   = (const float*)d_in[16];
  const float* flnihg = (const float*)d_in[17];
  const float* flnihb = (const float*)d_in[18];
  const float* flnhhg = (const float*)d_in[19];
  const float* flnhhb = (const float*)d_in[20];
  const float* flnhog = (const float*)d_in[21];
  const float* flnhob = (const float*)d_in[22];
  const float* bwih   = (const float*)d_in[23];
  const float* bbih   = (const float*)d_in[24];
  const float* bwhh   = (const float*)d_in[25];
  const float* bbhh   = (const float*)d_in[26];
  const float* blnihg = (const float*)d_in[27];
  const float* blnihb = (const float*)d_in[28];
  const float* blnhhg = (const float*)d_in[29];
  const float* blnhhb = (const float*)d_in[30];
  const float* blnhog = (const float*)d_in[31];
  const float* blnhob = (const float*)d_in[32];
  const float* attnw  = (const float*)d_in[33];
  const float* fc1w   = (const float*)d_in[34];
  const float* fc1b   = (const float*)d_in[35];
  const float* bn3g   = (const float*)d_in[36];
  const float* bn3b   = (const float*)d_in[37];
  const float* bn3m   = (const float*)d_in[38];
  const float* bn3v   = (const float*)d_in[39];
  const float* fc2w   = (const float*)d_in[40];
  const float* fc2b_  = (const float*)d_in[41];

  // Workspace layout (peak exactly 128 MiB), liveness overlays:
  //   c1o  f32 @  0..64M   (conv1 out; dead after conv2)
  //   seq  f32 @ 64..128M  (conv2 out; live through all k_xp chunks)
  //   xpF  f32 @  0..12M   (chunk; overlays dead c1o)
  //   xpB  f32 @ 12..24M
  //   hcat bf16@ 24..48M   (lstm out -> head)
  //   stateH   @ 48M       (96 KB)   stateC @ 48M+128K (96 KB)
  char* ws = (char*)d_ws;
  const size_t MB = 1048576;
  float* c1o    = (float*)(ws);
  float* seq    = (float*)(ws + 64*MB);
  float* xpF    = (float*)(ws);
  float* xpB    = (float*)(ws + 12*MB);
  u16*   hcat   = (u16*)  (ws + 24*MB);
  float* stateH = (float*)(ws + 48*MB);
  float* stateC = (float*)(ws + 48*MB + 131072);

  k_conv1<<<dim3(8,128),  256, 0, stream>>>(X,   c1w, c1b, bn1g, bn1b, bn1m, bn1v, c1o);
  k_conv2<<<dim3(8,2,128),256, 0, stream>>>(c1o, c2w, c2b, bn2g, bn2b, bn2m, bn2v, seq);
  for(int c = 0; c < 8; c++){
    k_xp  <<<dim3(256,2), 512, 0, stream>>>(seq, fwih, fbih, flnihg, flnihb,
                                                 bwih, bbih, blnihg, blnihb, xpF, xpB, c);
    k_lstm<<<dim3(128,2), 256, 0, stream>>>(xpF, xpB,
        fwhh, fbhh, flnhhg, flnhhb, flnhog, flnhob,
        bwhh, bbhh, blnhhg, blnhhb, blnhog, blnhob, hcat, stateH, stateC, c);
  }
  k_head<<<dim3(128),     256, 0, stream>>>(hcat, attnw, fc1w, fc1b,
      bn3g, bn3b, bn3m, bn3v, fc2w, fc2b_, (float*)d_out);
}